// Round 5
// baseline (468.819 us; speedup 1.0000x reference)
//
#include <hip/hip_runtime.h>
#include <cmath>

// Problem constants: x [B=8, C=256, H=80, W=80] fp32
#define BB 8
#define CC 256
#define HH 80
#define WW 80
#define HWSZ 6400              // 80*80
#define PLANE_FLOATS (CC * HWSZ)      // per-batch floats = 1,638,400
#define TENSOR_FLOATS (BB * PLANE_FLOATS) // 13,107,200

using short8v = __attribute__((ext_vector_type(8))) short;
using f32x4  = __attribute__((ext_vector_type(4))) float;

__device__ __forceinline__ float gelu_exact(float v) {
    return 0.5f * v * (1.0f + erff(v * 0.70710678118654752440f));
}

// fp32 -> bf16 (RNE)
__device__ __forceinline__ unsigned short f2bf(float f) {
    unsigned int u = __float_as_uint(f);
    unsigned int r = (u + 0x7FFFu + ((u >> 16) & 1u)) >> 16;
    return (unsigned short)r;
}
__device__ __forceinline__ float bf2f(unsigned short h) {
    return __uint_as_float(((unsigned int)h) << 16);
}

// ---------------------------------------------------------------------------
// Kernel -1: combine po+post:  Wcomb[o][0:256] = Wpost·Wpo,
// Wcomb[o][256:512] = Wpost, bcomb = Wpost·bpo + bpost.
// ---------------------------------------------------------------------------
__global__ __launch_bounds__(256)
void combine_po_post(const float* __restrict__ po_w, const float* __restrict__ po_b,
                     const float* __restrict__ post_w, const float* __restrict__ post_b,
                     float* __restrict__ Wcomb, float* __restrict__ bcomb)
{
    __shared__ float red[256];
    const int o = blockIdx.x;
    const int c = threadIdx.x;
    const float* prow = post_w + (size_t)o * 256;
    float s = 0.f;
#pragma unroll 4
    for (int m = 0; m < 256; ++m)
        s = fmaf(prow[m], po_w[(size_t)m * 256 + c], s);
    Wcomb[(size_t)o * 512 + c] = s;
    Wcomb[(size_t)o * 512 + 256 + c] = prow[c];
    // bias reduce
    red[c] = prow[c] * po_b[c];
    __syncthreads();
    for (int st = 128; st > 0; st >>= 1) {
        if (c < st) red[c] += red[c + st];
        __syncthreads();
    }
    if (c == 0) bcomb[o] = red[0] + post_b[o];
}

// ---------------------------------------------------------------------------
// Kernel 0: preconvert weights fp32 -> bf16 hi/lo in A-fragment order.
// idx = ((ks*16 + fi)*64 + l)*8 + j; element W[o][c], o = fi*16 + (l&15),
// c = ks*32 + (l>>4)*8 + j.
// ---------------------------------------------------------------------------
struct PreAll {
    const float* src[7];
    int stride[7];
    int runs[7];     // ksteps*1024
    int dstOff[7];
};

__global__ __launch_bounds__(256)
void preconvert_kernel(PreAll d, unsigned short* __restrict__ packH,
                       unsigned short* __restrict__ packL)
{
    const int m = blockIdx.y;
    const int r = blockIdx.x * 256 + threadIdx.x;
    if (r >= d.runs[m]) return;
    const int ks = r >> 10;
    const int rem = r & 1023;
    const int fi = rem >> 6;
    const int l = rem & 63;
    const int o = fi * 16 + (l & 15);
    const int c0 = ks * 32 + ((l >> 4)) * 8;
    const float* src = d.src[m] + (size_t)o * d.stride[m] + c0;
    short8v hv, lv;
#pragma unroll
    for (int j = 0; j < 8; ++j) {
        const float v = src[j];
        const unsigned short h = f2bf(v);
        const unsigned short lo = f2bf(v - bf2f(h));
        hv[j] = (short)h; lv[j] = (short)lo;
    }
    *(short8v*)(packH + d.dstOff[m] + (size_t)r * 8) = hv;
    *(short8v*)(packL + d.dstOff[m] + (size_t)r * 8) = lv;
}

// ---------------------------------------------------------------------------
// Kernel 1: BN + spectral gating (8 outputs/thread, register window).
// ---------------------------------------------------------------------------
struct GTab { float g[40]; };   // odd taps g[2*jj+1]

__global__ __launch_bounds__(256)
void bn_gate_kernel(const float* __restrict__ x,
                    const float* __restrict__ gamma, const float* __restrict__ beta,
                    const float* __restrict__ mean,  const float* __restrict__ var,
                    const float* __restrict__ ar,    const float* __restrict__ ai,
                    float* __restrict__ out, GTab gt)
{
    __shared__ float sv[HWSZ];
    const int blk = blockIdx.x;          // b*256 + c
    const int c = blk & (CC - 1);
    const float sc = gamma[c] * rsqrtf(var[c] + 1e-5f);
    const float sh = beta[c] - mean[c] * sc;
    const float a = ar[c], bgate = ai[c];
    const size_t base = (size_t)blk * HWSZ;

    const float4* x4 = (const float4*)(x + base);
    float4* s4 = (float4*)sv;
    for (int i = threadIdx.x; i < HWSZ / 4; i += 256) {
        float4 v = x4[i];
        v.x = fmaf(sc, v.x, sh); v.y = fmaf(sc, v.y, sh);
        v.z = fmaf(sc, v.z, sh); v.w = fmaf(sc, v.w, sh);
        s4[i] = v;
    }
    __syncthreads();

#pragma unroll 1
    for (int r = 0; r < 4; ++r) {
        const int gi = r * 256 + threadIdx.x;
        if (gi >= 800) break;
        const int y = gi / 10;
        const int x0 = (gi - y * 10) * 8;
        const float* row = sv + y * WW;

        float rbuf[88];
#pragma unroll
        for (int q = 0; q < 22; ++q) {
            int col = x0 + 4 * q;
            if (col >= 80) col -= 80;
            const float4 v = *(const float4*)&row[col];
            rbuf[4 * q + 0] = v.x; rbuf[4 * q + 1] = v.y;
            rbuf[4 * q + 2] = v.z; rbuf[4 * q + 3] = v.w;
        }
        float outv[8];
#pragma unroll
        for (int e = 0; e < 8; ++e) {
            float acc = 0.0f;
#pragma unroll
            for (int jj = 0; jj < 40; ++jj) {
                const int j = 2 * jj + 1;
                acc = fmaf(gt.g[jj], rbuf[80 + e - j], acc);
            }
            outv[e] = fmaf(a, rbuf[80 + e], bgate * acc);
        }
        float4 o0 = {outv[0], outv[1], outv[2], outv[3]};
        float4 o1 = {outv[4], outv[5], outv[6], outv[7]};
        *(float4*)&out[base + (size_t)y * WW + x0]     = o0;
        *(float4*)&out[base + (size_t)y * WW + x0 + 4] = o1;
    }
}

// ---------------------------------------------------------------------------
// Kernel 2: MFMA bf16-split-3 GEMM. M=256 full, N-tile=64, K = KS*32.
// 3-deep X register prefetch (xbuf[3]); A-prefetch issued BEFORE X-issue so
// the MFMA's vmcnt wait keeps 2 X batches in flight (in-order vmcnt).
// KS=16 reads K 0..255 from X, 256..511 from X2.
// EPI: 0 = +bias, 1 = +bias+gelu, 2 = +bias+residual
// ---------------------------------------------------------------------------
template <int EPI, int KS>
__global__ __launch_bounds__(256)
void gemm_mfma(const float* __restrict__ X, const float* __restrict__ X2,
               const unsigned short* __restrict__ Wh,
               const unsigned short* __restrict__ Wl,
               const float* __restrict__ bias,
               const float* __restrict__ res, float* __restrict__ Y)
{
    __shared__ short8v sB[2][2][256];   // [buf][hi/lo][slot], 16 KB

    const int bz = blockIdx.z;
    const int nBase = blockIdx.x * 64;
    const int t = threadIdx.x;
    const int l = t & 63;
    const int w = t >> 6;

    const float* Xb  = X + (size_t)bz * PLANE_FLOATS + nBase;
    const float* X2b = (KS == 16) ? (X2 + (size_t)bz * PLANE_FLOATS + nBase) : nullptr;
    float* Yb = Y + (size_t)bz * PLANE_FLOATS;

    const int sn = t & 63;
    const int scg = t >> 6;
    const int slot = ((sn >> 4) * 64) + scg * 16 + (sn & 15);

    f32x4 acc[4][4];
#pragma unroll
    for (int m = 0; m < 4; ++m)
#pragma unroll
        for (int n2 = 0; n2 < 4; ++n2) acc[m][n2] = (f32x4){0.f, 0.f, 0.f, 0.f};

    // ---- prologue: A frags ks=0 FIRST, then X issues k=0,1,2
    short8v ah[4], al[4];
    {
        const size_t fb = ((size_t)(w * 4) * 64 + l) * 8;
#pragma unroll
        for (int m = 0; m < 4; ++m) {
            ah[m] = *(const short8v*)(Wh + fb + (size_t)m * 512);
            al[m] = *(const short8v*)(Wl + fb + (size_t)m * 512);
        }
    }
    float xbuf[3][8];
#pragma unroll
    for (int d = 0; d < 3; ++d) {
        if (d < KS) {
            const float* src = (KS == 16 && d >= 8) ? X2b : Xb;
            const int kk = (KS == 16 && d >= 8) ? d - 8 : d;
#pragma unroll
            for (int j = 0; j < 8; ++j)
                xbuf[d][j] = src[(size_t)(kk * 32 + scg * 8 + j) * HWSZ + sn];
        }
    }
    {
        short8v hv, lv;
#pragma unroll
        for (int j = 0; j < 8; ++j) {
            const unsigned short h = f2bf(xbuf[0][j]);
            const unsigned short lo = f2bf(xbuf[0][j] - bf2f(h));
            hv[j] = (short)h; lv[j] = (short)lo;
        }
        sB[0][0][slot] = hv; sB[0][1][slot] = lv;
    }
    __syncthreads();

#pragma unroll
    for (int ks = 0; ks < KS; ++ks) {
        const int p = ks & 1;
        // 1. B frags from LDS (lane-linear, conflict-free)
        short8v bh[4], bl[4];
#pragma unroll
        for (int n2 = 0; n2 < 4; ++n2) {
            bh[n2] = sB[p][0][n2 * 64 + l];
            bl[n2] = sB[p][1][n2 * 64 + l];
        }
        // 2. A prefetch for ks+1 (BEFORE the X issue: vmcnt ordering)
        short8v ah2[4], al2[4];
        if (ks + 1 < KS) {
            const size_t fb = ((size_t)((ks + 1) * 16 + w * 4) * 64 + l) * 8;
#pragma unroll
            for (int m = 0; m < 4; ++m) {
                ah2[m] = *(const short8v*)(Wh + fb + (size_t)m * 512);
                al2[m] = *(const short8v*)(Wl + fb + (size_t)m * 512);
            }
        }
        // 3. X issue for ks+3 into the just-freed buffer slot
        if (ks + 3 < KS) {
            const int kn = ks + 3;
            const float* src = (KS == 16 && kn >= 8) ? X2b : Xb;
            const int kk = (KS == 16 && kn >= 8) ? kn - 8 : kn;
#pragma unroll
            for (int j = 0; j < 8; ++j)
                xbuf[ks % 3][j] = src[(size_t)(kk * 32 + scg * 8 + j) * HWSZ + sn];
        }
        // 4. split-3 MFMA for ks
#pragma unroll
        for (int m = 0; m < 4; ++m)
#pragma unroll
            for (int n2 = 0; n2 < 4; ++n2) {
                acc[m][n2] = __builtin_amdgcn_mfma_f32_16x16x32_bf16(
                    ah[m], bh[n2], acc[m][n2], 0, 0, 0);
                acc[m][n2] = __builtin_amdgcn_mfma_f32_16x16x32_bf16(
                    ah[m], bl[n2], acc[m][n2], 0, 0, 0);
                acc[m][n2] = __builtin_amdgcn_mfma_f32_16x16x32_bf16(
                    al[m], bh[n2], acc[m][n2], 0, 0, 0);
            }
        // 5. convert + stage ks+1, single barrier
        if (ks + 1 < KS) {
            short8v hv, lv;
#pragma unroll
            for (int j = 0; j < 8; ++j) {
                const float v = xbuf[(ks + 1) % 3][j];
                const unsigned short h = f2bf(v);
                const unsigned short lo = f2bf(v - bf2f(h));
                hv[j] = (short)h; lv[j] = (short)lo;
            }
            sB[p ^ 1][0][slot] = hv; sB[p ^ 1][1][slot] = lv;
            __syncthreads();
#pragma unroll
            for (int m = 0; m < 4; ++m) { ah[m] = ah2[m]; al[m] = al2[m]; }
        }
    }

    // epilogue: C/D layout col = l&15, row = (l>>4)*4 + r
    const int col = l & 15, g = l >> 4;
#pragma unroll
    for (int m = 0; m < 4; ++m) {
        const int o0 = w * 64 + m * 16 + g * 4;
#pragma unroll
        for (int r = 0; r < 4; ++r) {
            const int o = o0 + r;
            const float bo = bias[o];
            float* yrow = Yb + (size_t)o * HWSZ + nBase;
            const float* rrow = (EPI == 2)
                ? (res + ((size_t)bz * CC + o) * HWSZ + nBase) : nullptr;
#pragma unroll
            for (int n2 = 0; n2 < 4; ++n2) {
                const int n = n2 * 16 + col;
                float v = acc[m][n2][r] + bo;
                if (EPI == 1) v = gelu_exact(v);
                if (EPI == 2) v += rrow[n];
                yrow[n] = v;
            }
        }
    }
}

// ---------------------------------------------------------------------------
// Kernel 3: depthwise 3x3 + bias + GELU; 4 outputs/thread, float4 loads.
// ---------------------------------------------------------------------------
__global__ __launch_bounds__(256)
void dwconv_gelu_kernel(const float* __restrict__ in, const float* __restrict__ w,
                        const float* __restrict__ bias, float* __restrict__ out)
{
    const int g = blockIdx.x * 256 + threadIdx.x;   // < 3,276,800
    const int plane = g / 1600;                     // b*256 + c
    const int pg = g - plane * 1600;
    const int c = plane & (CC - 1);
    const int y = pg / 20;
    const int x0 = (pg - y * 20) * 4;
    const float* p = in + (size_t)plane * HWSZ;

    float rb[3][12];
#pragma unroll
    for (int ky = 0; ky < 3; ++ky) {
        const int yy = y + ky - 1;
        const bool yok = (yy >= 0) && (yy < HH);
        const float* prow = p + yy * WW;
#pragma unroll
        for (int q = 0; q < 3; ++q) {
            const int cx = x0 + 4 * q - 4;
            float4 v = {0.f, 0.f, 0.f, 0.f};
            if (yok && cx >= 0 && cx < WW) v = *(const float4*)&prow[cx];
            rb[ky][4 * q + 0] = v.x; rb[ky][4 * q + 1] = v.y;
            rb[ky][4 * q + 2] = v.z; rb[ky][4 * q + 3] = v.w;
        }
    }
    const float* wc = w + c * 9;
    float wv[9];
#pragma unroll
    for (int k = 0; k < 9; ++k) wv[k] = wc[k];
    const float bo = bias[c];

    float4 res;
    float* rp = (float*)&res;
#pragma unroll
    for (int e = 0; e < 4; ++e) {
        float s = bo;
#pragma unroll
        for (int ky = 0; ky < 3; ++ky)
#pragma unroll
            for (int kx = 0; kx < 3; ++kx)
                s = fmaf(wv[ky * 3 + kx], rb[ky][e + kx + 3], s);
        rp[e] = gelu_exact(s);
    }
    *(float4*)&out[(size_t)plane * HWSZ + (size_t)y * WW + x0] = res;
}

// ---------------------------------------------------------------------------
extern "C" void kernel_launch(void* const* d_in, const int* in_sizes, int n_in,
                              void* d_out, int out_size, void* d_ws, size_t ws_size,
                              hipStream_t stream)
{
    const float* x        = (const float*)d_in[0];
    const float* bn_gamma = (const float*)d_in[1];
    const float* bn_beta  = (const float*)d_in[2];
    const float* bn_mean  = (const float*)d_in[3];
    const float* bn_var   = (const float*)d_in[4];
    const float* alpha_r  = (const float*)d_in[5];
    const float* alpha_i  = (const float*)d_in[6];
    const float* pi_w     = (const float*)d_in[7];
    const float* pi_b     = (const float*)d_in[8];
    const float* dw_w     = (const float*)d_in[9];
    const float* dw_b     = (const float*)d_in[10];
    const float* fpw_w    = (const float*)d_in[11];
    const float* fpw_b    = (const float*)d_in[12];
    const float* ffn1_w   = (const float*)d_in[13];
    const float* ffn1_b   = (const float*)d_in[14];
    const float* ffn2_w   = (const float*)d_in[15];
    const float* ffn2_b   = (const float*)d_in[16];
    const float* po_w     = (const float*)d_in[17];
    const float* po_b     = (const float*)d_in[18];
    const float* post_w   = (const float*)d_in[19];
    const float* post_b   = (const float*)d_in[20];

    float* bufA = (float*)d_ws;                       // gated h (res2)
    float* bufB = bufA + TENSOR_FLOATS;
    float* bufC = bufB + TENSOR_FLOATS;
    float* bufD = (float*)d_out;                      // y3b scratch / final out
    unsigned short* packH = (unsigned short*)(bufC + TENSOR_FLOATS);
    unsigned short* packL = packH + 524288;
    float* Wcomb = (float*)(packL + 524288);          // 256x512
    float* bcomb = Wcomb + 131072;                    // 256

    // gating taps
    GTab gt;
    for (int jj = 0; jj < 40; ++jj) {
        const int j = 2 * jj + 1;
        double s = 0.0;
        for (int k = 1; k <= 39; ++k)
            s += sin(2.0 * 3.14159265358979323846 * (double)k * (double)j / 80.0);
        gt.g[jj] = (float)(-s / 40.0);
    }

    // weight preconvert: pi, fpw, ffn1a, ffn1b, ffn2(K512), comb(K512)
    PreAll pd;
    pd.src[0] = pi_w;              pd.stride[0] = 256; pd.runs[0] = 8192;  pd.dstOff[0] = 0;
    pd.src[1] = fpw_w;             pd.stride[1] = 256; pd.runs[1] = 8192;  pd.dstOff[1] = 65536;
    pd.src[2] = ffn1_w;            pd.stride[2] = 256; pd.runs[2] = 8192;  pd.dstOff[2] = 131072;
    pd.src[3] = ffn1_w + 256*256;  pd.stride[3] = 256; pd.runs[3] = 8192;  pd.dstOff[3] = 196608;
    pd.src[4] = ffn2_w;            pd.stride[4] = 512; pd.runs[4] = 16384; pd.dstOff[4] = 262144;
    pd.src[5] = Wcomb;             pd.stride[5] = 512; pd.runs[5] = 16384; pd.dstOff[5] = 393216;
    pd.src[6] = pi_w;              pd.stride[6] = 256; pd.runs[6] = 0;     pd.dstOff[6] = 0;

    const dim3 gGrid(HWSZ / 64, 1, BB);   // 100 x 1 x 8
    const dim3 gBlk(256);

    // -1. combine po+post weights
    combine_po_post<<<256, 256, 0, stream>>>(po_w, po_b, post_w, post_b, Wcomb, bcomb);
    // 0. preconvert weights (6 matrices)
    preconvert_kernel<<<dim3(64, 6), 256, 0, stream>>>(pd, packH, packL);
    // 1. BN + spectral gating -> bufA (res2)
    bn_gate_kernel<<<BB * CC, 256, 0, stream>>>(x, bn_gamma, bn_beta, bn_mean,
                                                bn_var, alpha_r, alpha_i, bufA, gt);
    // 2. proj_in -> bufB (t)
    gemm_mfma<0, 8><<<gGrid, gBlk, 0, stream>>>(bufA, nullptr, packH, packL,
                                                pi_b, nullptr, bufB);
    // 3. dw3x3 + GELU -> bufC (y1)
    dwconv_gelu_kernel<<<TENSOR_FLOATS / 1024, 256, 0, stream>>>(bufB, dw_w, dw_b, bufC);
    // 4. fpw -> bufB (y2)
    gemm_mfma<0, 8><<<gGrid, gBlk, 0, stream>>>(bufC, nullptr, packH + 65536,
                                                packL + 65536, fpw_b, nullptr, bufB);
    // 5a. ffn1 rows [0,256) + GELU -> bufC (y3a)
    gemm_mfma<1, 8><<<gGrid, gBlk, 0, stream>>>(bufB, nullptr, packH + 131072,
                                                packL + 131072, ffn1_b, nullptr, bufC);
    // 5b. ffn1 rows [256,512) + GELU -> bufD=d_out scratch (y3b)
    gemm_mfma<1, 8><<<gGrid, gBlk, 0, stream>>>(bufB, nullptr, packH + 196608,
                                                packL + 196608, ffn1_b + 256, nullptr, bufD);
    // 6. ffn2, K=512 over (bufC, bufD) -> bufB (y4)
    gemm_mfma<0, 16><<<gGrid, gBlk, 0, stream>>>(bufC, bufD, packH + 262144,
                                                 packL + 262144, ffn2_b, nullptr, bufB);
    // 7. fused (po+post), K=512 over (y4=bufB, res2=bufA), +x -> d_out
    gemm_mfma<2, 16><<<gGrid, gBlk, 0, stream>>>(bufB, bufA, packH + 393216,
                                                 packL + 393216, bcomb, x, (float*)d_out);
}